// Round 3
// baseline (832.072 us; speedup 1.0000x reference)
//
#include <hip/hip_runtime.h>

#define J 17
#define VO 289            // 17*17
#define NB 8192
#define DIN 2048
#define EPSB 1e-5f

typedef __attribute__((ext_vector_type(8))) short bf16x8;
typedef __attribute__((ext_vector_type(4))) float f32x4;

// skeleton adjacency (incl. self), hard-coded from SKEL
__device__ __constant__ int d_deg[J] = {3,4,4,3,3,5,5,3,3,2,2,4,4,3,3,2,2};
__device__ __constant__ int d_nbr[J][5] = {
  {0,1,2,0,0},{0,1,2,3,0},{0,1,2,4,0},{1,3,5,0,0},{2,4,6,0,0},
  {3,5,6,7,11},{4,5,6,8,12},{5,7,9,0,0},{6,8,10,0,0},{7,9,0,0,0},
  {8,10,0,0,0},{5,11,12,13,0},{6,11,12,14,0},{11,13,15,0,0},{12,14,16,0,0},
  {13,15,0,0,0},{14,16,0,0,0}};

__device__ inline unsigned short f2bf(float x){
  unsigned u = __float_as_uint(x);
  return (unsigned short)((u + 0x7fffu + ((u>>16)&1u)) >> 16);   // RNE
}

__global__ void zero_stats(float* p, int n) {
  int i = blockIdx.x*blockDim.x + threadIdx.x;
  int stride = gridDim.x*blockDim.x;
  for (; i < n; i += stride) p[i] = 0.f;
}

// -------- prepass: W0 [17][2048][17] f32 -> Wbt [17][32 cols][2048 k] bf16 (cols 17..31 zero)
__global__ __launch_bounds__(256) void wconv_kernel(
    const float* __restrict__ W0, unsigned short* __restrict__ Wbt)
{
  int t = blockIdx.x*256 + threadIdx.x;    // t = v*2048 + k  (exactly 34816 threads)
  int v = t >> 11, k = t & 2047;
  const float* src = W0 + (size_t)t*J;
  unsigned short* dst = Wbt + ((size_t)v*32 << 11) + k;
  #pragma unroll
  for (int o=0;o<J;++o)  dst[(size_t)o<<11] = f2bf(src[o]);
  #pragma unroll
  for (int o=J;o<32;++o) dst[(size_t)o<<11] = 0;
}

// -------- conv0: per-vertex GEMM [8192,2048]x[2048,17->32] via bf16 MFMA + bias + BN stats
// grid (64 row-chunks of 128, 17 v), block 256 (4 waves). BM=128, BN=32, BK=64.
// A staged f32->bf16 in XOR-swizzled LDS (double-buffered), B read from Wbt (L2-hot).
__global__ __launch_bounds__(256) void conv0_kernel(
    const float* __restrict__ feat, const unsigned short* __restrict__ Wbt,
    const float* __restrict__ b0, float* __restrict__ C,
    float* __restrict__ sS, float* __restrict__ sQ)
{
  const int v = blockIdx.y;
  const int tid = threadIdx.x, w = tid>>6, l = tid&63;
  const int lo = l&15, oc = l>>4;
  const int rowBlk = blockIdx.x*128;

  __shared__ __align__(16) unsigned short Abuf[2][128*64];
  __shared__ float bstat[34];
  if (tid < 34) bstat[tid] = 0.f;

  f32x4 acc[2][2];
  #pragma unroll
  for (int m=0;m<2;++m)
    #pragma unroll
    for (int n=0;n<2;++n)
      acc[m][n] = (f32x4){0.f,0.f,0.f,0.f};

  const unsigned short* Wv = Wbt + ((size_t)v*32 << 11);

  auto stage = [&](int buf, int kc) {
    const int kq = lo*4;
    #pragma unroll
    for (int i=0;i<8;++i) {
      const int r = w*32 + i*4 + oc;
      const float4 fv = *(const float4*)(feat + ((size_t)(rowBlk + r)*J + v)*DIN + kc*64 + kq);
      ushort4 hv;
      hv.x = f2bf(fv.x); hv.y = f2bf(fv.y); hv.z = f2bf(fv.z); hv.w = f2bf(fv.w);
      const int idx = (r*64 + kq) ^ ((r&7)<<3);   // ushort units; XOR-swizzle (16B granular)
      *(ushort4*)&Abuf[buf][idx] = hv;
    }
  };

  stage(0, 0);
  __syncthreads();

  const int r0 = w*32 + lo, r1 = w*32 + 16 + lo;
  const int sw0 = (r0&7)<<3, sw1 = (r1&7)<<3;

  for (int kc=0; kc<DIN/64; ++kc) {
    const int buf = kc & 1;
    if (kc < DIN/64 - 1) stage(buf^1, kc+1);
    #pragma unroll
    for (int ks=0; ks<2; ++ks) {
      const int kb = ks*32 + oc*8;
      bf16x8 a0 = *(const bf16x8*)&Abuf[buf][(r0*64 + kb) ^ sw0];
      bf16x8 a1 = *(const bf16x8*)&Abuf[buf][(r1*64 + kb) ^ sw1];
      const size_t kg = (size_t)kc*64 + kb;
      bf16x8 b0f = *(const bf16x8*)(Wv + ((size_t)lo      << 11) + kg);
      bf16x8 b1f = *(const bf16x8*)(Wv + ((size_t)(16+lo) << 11) + kg);
      acc[0][0] = __builtin_amdgcn_mfma_f32_16x16x32_bf16(a0, b0f, acc[0][0], 0,0,0);
      acc[0][1] = __builtin_amdgcn_mfma_f32_16x16x32_bf16(a0, b1f, acc[0][1], 0,0,0);
      acc[1][0] = __builtin_amdgcn_mfma_f32_16x16x32_bf16(a1, b0f, acc[1][0], 0,0,0);
      acc[1][1] = __builtin_amdgcn_mfma_f32_16x16x32_bf16(a1, b1f, acc[1][1], 0,0,0);
    }
    __syncthreads();
  }

  // epilogue: bias, C store, BN stats.  C/D layout: col=lane&15, row=(lane>>4)*4+reg
  const float bias0 = b0[v*J + lo];
  const float bias1 = (lo==0) ? b0[v*J + 16] : 0.f;
  float s0=0.f,q0=0.f,s1=0.f,q1=0.f;
  #pragma unroll
  for (int m=0;m<2;++m) {
    #pragma unroll
    for (int r=0;r<4;++r) {
      const int row = rowBlk + w*32 + m*16 + oc*4 + r;
      const float h0 = acc[m][0][r] + bias0;
      C[(size_t)row*VO + v*J + lo] = h0;
      s0 += h0; q0 += h0*h0;
      if (lo==0) {
        const float h1 = acc[m][1][r] + bias1;
        C[(size_t)row*VO + v*J + 16] = h1;
        s1 += h1; q1 += h1*h1;
      }
    }
  }
  s0 += __shfl_xor(s0,16); s0 += __shfl_xor(s0,32);
  q0 += __shfl_xor(q0,16); q0 += __shfl_xor(q0,32);
  s1 += __shfl_xor(s1,16); s1 += __shfl_xor(s1,32);
  q1 += __shfl_xor(q1,16); q1 += __shfl_xor(q1,32);
  if (l < 16) { atomicAdd(&bstat[lo], s0); atomicAdd(&bstat[17+lo], q0); }
  if (l == 0) { atomicAdd(&bstat[16], s1); atomicAdd(&bstat[33], q1); }
  __syncthreads();
  if (tid < 17)       atomicAdd(&sS[v*J + tid], bstat[tid]);
  else if (tid < 34)  atomicAdd(&sQ[v*J + (tid-17)], bstat[tid]);
}

// -------- chain: BN_j -> adjacency -> ReLU [-> +resid / store F] [-> conv_{j+1} + stats]
// 1024 blocks x 8 rows, block 256 (4 waves; 2 rows per wave, wave-independent, no per-row barriers)
template<int RESID,int WRITEF,int CONV>
__global__ __launch_bounds__(256) void chain_kernel(
  const float* __restrict__ Cin, float* __restrict__ Cout,
  float* __restrict__ F,
  const float* __restrict__ sS, const float* __restrict__ sQ,
  const float* __restrict__ g, const float* __restrict__ be,
  const float* __restrict__ Wc, const float* __restrict__ bc,
  float* __restrict__ nS, float* __restrict__ nQ)
{
  __shared__ float wsm[J*J*J];
  __shared__ float bb[VO];
  __shared__ float aC[VO], cC[VO];
  __shared__ float hb1[4][VO], hb2[4][VO];
  __shared__ float ssum[VO], ssq[VO];
  const int tid = threadIdx.x, wv = tid>>6, lane = tid&63;

  if (CONV) {
    for (int i=tid;i<J*J*J;i+=256) wsm[i]=Wc[i];
    for (int i=tid;i<VO;i+=256) bb[i]=bc[i];
  }
  for (int i=tid;i<VO;i+=256) {
    float mu  = sS[i]*(1.f/NB);
    float var = sQ[i]*(1.f/NB) - mu*mu;
    float rs  = rsqrtf(var + EPSB);
    float A = rs*g[i];
    aC[i]=A; cC[i]=be[i]-mu*A;
    ssum[i]=0.f; ssq[i]=0.f;
  }
  __syncthreads();

  float sl[5], ql[5];
  #pragma unroll
  for (int s=0;s<5;++s){ sl[s]=0.f; ql[s]=0.f; }

  for (int it=0; it<2; ++it) {
    const int row = blockIdx.x*8 + wv*2 + it;
    const float* cr = Cin + (size_t)row*VO;
    #pragma unroll
    for (int s=0;s<5;++s) {
      int vo = lane + 64*s;
      if (vo<VO) hb1[wv][vo] = cr[vo]*aC[vo] + cC[vo];
    }
    asm volatile("s_waitcnt lgkmcnt(0)" ::: "memory");
    #pragma unroll
    for (int s=0;s<5;++s) {
      int vo = lane + 64*s;
      if (vo<VO) {
        int vtx = vo/J, o = vo - vtx*J;
        float a = 0.f;
        int dg = d_deg[vtx];
        for (int e=0;e<dg;++e) a += hb1[wv][d_nbr[vtx][e]*J + o];
        float h = a>0.f ? a : 0.f;
        size_t gi = (size_t)row*VO + vo;
        if (RESID)  h += F[gi];
        if (WRITEF) F[gi] = h;
        if (CONV) hb2[wv][vo] = h;
        else      Cout[gi] = h;
      }
    }
    if (CONV) {
      asm volatile("s_waitcnt lgkmcnt(0)" ::: "memory");
      #pragma unroll
      for (int s=0;s<5;++s) {
        int vo = lane + 64*s;
        if (vo<VO) {
          int vtx = vo/J, o = vo - vtx*J;
          float a = bb[vo];
          const float* wrow = &wsm[vtx*VO + o];
          const float* hrow = &hb2[wv][vtx*J];
          #pragma unroll
          for (int d=0;d<J;++d) a += hrow[d]*wrow[d*J];
          Cout[(size_t)row*VO + vo] = a;
          sl[s] += a; ql[s] += a*a;
        }
      }
    }
  }

  if (CONV) {
    #pragma unroll
    for (int s=0;s<5;++s) {
      int vo = lane + 64*s;
      if (vo<VO) { atomicAdd(&ssum[vo], sl[s]); atomicAdd(&ssq[vo], ql[s]); }
    }
    __syncthreads();
    for (int i=tid;i<VO;i+=256) {
      atomicAdd(&nS[i], ssum[i]);
      atomicAdd(&nQ[i], ssq[i]);
    }
  }
}

extern "C" void kernel_launch(void* const* d_in, const int* in_sizes, int n_in,
                              void* d_out, int out_size, void* d_ws, size_t ws_size,
                              hipStream_t stream)
{
  (void)in_sizes; (void)n_in; (void)out_size; (void)ws_size;
  const float* img = (const float*)d_in[0];
  const float* W0  = (const float*)d_in[1];
  const float* b0  = (const float*)d_in[2];
  const float* g0  = (const float*)d_in[3];
  const float* be0 = (const float*)d_in[4];
  const float* Wr  = (const float*)d_in[5];
  const float* br  = (const float*)d_in[6];
  const float* gr  = (const float*)d_in[7];
  const float* ber = (const float*)d_in[8];

  float* ws = (float*)d_ws;
  float* sS = ws;                              // 9*289 used (4096 reserved)
  float* sQ = ws + 4096;                       // 9*289 used (4096 reserved)
  unsigned short* Wbt = (unsigned short*)(ws + 8192);   // 17*32*2048 bf16 = 557056 floats
  float* Ca = ws + 8192 + 557056;
  float* Cb = Ca + (size_t)NB*VO;
  float* F  = Cb + (size_t)NB*VO;
  float* out = (float*)d_out;

  zero_stats<<<8,256,0,stream>>>(ws, 8192);
  wconv_kernel<<<136,256,0,stream>>>(W0, Wbt);

  conv0_kernel<<<dim3(64,17),256,0,stream>>>(img, Wbt, b0, Ca, sS, sQ);

  const int W1 = J*J*J;
  // j=0: BN0(g0,be0) -> feat0 (store F), conv1 -> stats1
  chain_kernel<0,1,1><<<1024,256,0,stream>>>(Ca, Cb, F, sS,        sQ,        g0,        be0,
                                             Wr+0*W1, br+0*VO, sS+1*VO, sQ+1*VO);
  // j=1
  chain_kernel<0,0,1><<<1024,256,0,stream>>>(Cb, Ca, F, sS+1*VO, sQ+1*VO, gr+0*VO, ber+0*VO,
                                             Wr+1*W1, br+1*VO, sS+2*VO, sQ+2*VO);
  // j=2: resid + store F
  chain_kernel<1,1,1><<<1024,256,0,stream>>>(Ca, Cb, F, sS+2*VO, sQ+2*VO, gr+1*VO, ber+1*VO,
                                             Wr+2*W1, br+2*VO, sS+3*VO, sQ+3*VO);
  // j=3
  chain_kernel<0,0,1><<<1024,256,0,stream>>>(Cb, Ca, F, sS+3*VO, sQ+3*VO, gr+2*VO, ber+2*VO,
                                             Wr+3*W1, br+3*VO, sS+4*VO, sQ+4*VO);
  // j=4
  chain_kernel<1,1,1><<<1024,256,0,stream>>>(Ca, Cb, F, sS+4*VO, sQ+4*VO, gr+3*VO, ber+3*VO,
                                             Wr+4*W1, br+4*VO, sS+5*VO, sQ+5*VO);
  // j=5
  chain_kernel<0,0,1><<<1024,256,0,stream>>>(Cb, Ca, F, sS+5*VO, sQ+5*VO, gr+4*VO, ber+4*VO,
                                             Wr+5*W1, br+5*VO, sS+6*VO, sQ+6*VO);
  // j=6
  chain_kernel<1,1,1><<<1024,256,0,stream>>>(Ca, Cb, F, sS+6*VO, sQ+6*VO, gr+5*VO, ber+5*VO,
                                             Wr+6*W1, br+6*VO, sS+7*VO, sQ+7*VO);
  // j=7
  chain_kernel<0,0,1><<<1024,256,0,stream>>>(Cb, Ca, F, sS+7*VO, sQ+7*VO, gr+6*VO, ber+6*VO,
                                             Wr+7*W1, br+7*VO, sS+8*VO, sQ+8*VO);
  // j=8: BN8 -> adj -> relu -> + feat3 -> d_out
  chain_kernel<1,0,0><<<1024,256,0,stream>>>(Ca, out, F, sS+8*VO, sQ+8*VO, gr+7*VO, ber+7*VO,
                                             nullptr, nullptr, nullptr, nullptr);
}

// Round 4
// 580.034 us; speedup vs baseline: 1.4345x; 1.4345x over previous
//
#include <hip/hip_runtime.h>

#define J 17
#define JP 18             // padded inner dim (2-way LDS bank alias = free)
#define VO 289            // 17*17
#define NB 8192
#define DIN 2048
#define EPSB 1e-5f

typedef __attribute__((ext_vector_type(8))) short bf16x8;
typedef __attribute__((ext_vector_type(4))) float f32x4;

// adjacency (incl. self) as bitmasks, from SKEL
__device__ __constant__ unsigned ADJM[J] = {
  0x7u, 0xFu, 0x17u, 0x2Au, 0x54u, 0x8E8u, 0x1170u, 0x2A0u, 0x540u,
  0x280u, 0x500u, 0x3820u, 0x5840u, 0xA800u, 0x15000u, 0xA000u, 0x14000u};

__device__ inline unsigned short f2bf(float x){
  unsigned u = __float_as_uint(x);
  return (unsigned short)((u + 0x7fffu + ((u>>16)&1u)) >> 16);   // RNE
}

__global__ void zero_stats(float* p, int n) {
  int i = blockIdx.x*blockDim.x + threadIdx.x;
  int stride = gridDim.x*blockDim.x;
  for (; i < n; i += stride) p[i] = 0.f;
}

// -------- prepass: W0 [17][2048][17] f32 -> Wbt [17][32 cols][2048 k] bf16 (cols 17..31 zero)
__global__ __launch_bounds__(256) void wconv_kernel(
    const float* __restrict__ W0, unsigned short* __restrict__ Wbt)
{
  int t = blockIdx.x*256 + threadIdx.x;    // t = v*2048 + k  (exactly 34816 threads)
  int v = t >> 11, k = t & 2047;
  const float* src = W0 + (size_t)t*J;
  unsigned short* dst = Wbt + ((size_t)v*32 << 11) + k;
  #pragma unroll
  for (int o=0;o<J;++o)  dst[(size_t)o<<11] = f2bf(src[o]);
  #pragma unroll
  for (int o=J;o<32;++o) dst[(size_t)o<<11] = 0;
}

// -------- conv0: per-vertex GEMM [8192,2048]x[2048,17->32] via bf16 MFMA + bias + BN stats
// (unchanged from round 3 except replica stats target)
__global__ __launch_bounds__(256) void conv0_kernel(
    const float* __restrict__ feat, const unsigned short* __restrict__ Wbt,
    const float* __restrict__ b0, float* __restrict__ C,
    float* __restrict__ stat0)
{
  const int v = blockIdx.y;
  const int tid = threadIdx.x, w = tid>>6, l = tid&63;
  const int lo = l&15, oc = l>>4;
  const int rowBlk = blockIdx.x*128;

  __shared__ __align__(16) unsigned short Abuf[2][128*64];
  __shared__ float bstat[34];
  if (tid < 34) bstat[tid] = 0.f;

  f32x4 acc[2][2];
  #pragma unroll
  for (int m=0;m<2;++m)
    #pragma unroll
    for (int n=0;n<2;++n)
      acc[m][n] = (f32x4){0.f,0.f,0.f,0.f};

  const unsigned short* Wv = Wbt + ((size_t)v*32 << 11);

  auto stage = [&](int buf, int kc) {
    const int kq = lo*4;
    #pragma unroll
    for (int i=0;i<8;++i) {
      const int r = w*32 + i*4 + oc;
      const float4 fv = *(const float4*)(feat + ((size_t)(rowBlk + r)*J + v)*DIN + kc*64 + kq);
      ushort4 hv;
      hv.x = f2bf(fv.x); hv.y = f2bf(fv.y); hv.z = f2bf(fv.z); hv.w = f2bf(fv.w);
      const int idx = (r*64 + kq) ^ ((r&7)<<3);
      *(ushort4*)&Abuf[buf][idx] = hv;
    }
  };

  stage(0, 0);
  __syncthreads();

  const int r0 = w*32 + lo, r1 = w*32 + 16 + lo;
  const int sw0 = (r0&7)<<3, sw1 = (r1&7)<<3;

  for (int kc=0; kc<DIN/64; ++kc) {
    const int buf = kc & 1;
    if (kc < DIN/64 - 1) stage(buf^1, kc+1);
    #pragma unroll
    for (int ks=0; ks<2; ++ks) {
      const int kb = ks*32 + oc*8;
      bf16x8 a0 = *(const bf16x8*)&Abuf[buf][(r0*64 + kb) ^ sw0];
      bf16x8 a1 = *(const bf16x8*)&Abuf[buf][(r1*64 + kb) ^ sw1];
      const size_t kg = (size_t)kc*64 + kb;
      bf16x8 b0f = *(const bf16x8*)(Wv + ((size_t)lo      << 11) + kg);
      bf16x8 b1f = *(const bf16x8*)(Wv + ((size_t)(16+lo) << 11) + kg);
      acc[0][0] = __builtin_amdgcn_mfma_f32_16x16x32_bf16(a0, b0f, acc[0][0], 0,0,0);
      acc[0][1] = __builtin_amdgcn_mfma_f32_16x16x32_bf16(a0, b1f, acc[0][1], 0,0,0);
      acc[1][0] = __builtin_amdgcn_mfma_f32_16x16x32_bf16(a1, b0f, acc[1][0], 0,0,0);
      acc[1][1] = __builtin_amdgcn_mfma_f32_16x16x32_bf16(a1, b1f, acc[1][1], 0,0,0);
    }
    __syncthreads();
  }

  const float bias0 = b0[v*J + lo];
  const float bias1 = (lo==0) ? b0[v*J + 16] : 0.f;
  float s0=0.f,q0=0.f,s1=0.f,q1=0.f;
  #pragma unroll
  for (int m=0;m<2;++m) {
    #pragma unroll
    for (int r=0;r<4;++r) {
      const int row = rowBlk + w*32 + m*16 + oc*4 + r;
      const float h0 = acc[m][0][r] + bias0;
      C[(size_t)row*VO + v*J + lo] = h0;
      s0 += h0; q0 += h0*h0;
      if (lo==0) {
        const float h1 = acc[m][1][r] + bias1;
        C[(size_t)row*VO + v*J + 16] = h1;
        s1 += h1; q1 += h1*h1;
      }
    }
  }
  s0 += __shfl_xor(s0,16); s0 += __shfl_xor(s0,32);
  q0 += __shfl_xor(q0,16); q0 += __shfl_xor(q0,32);
  s1 += __shfl_xor(s1,16); s1 += __shfl_xor(s1,32);
  q1 += __shfl_xor(q1,16); q1 += __shfl_xor(q1,32);
  if (l < 16) { atomicAdd(&bstat[lo], s0); atomicAdd(&bstat[17+lo], q0); }
  if (l == 0) { atomicAdd(&bstat[16], s1); atomicAdd(&bstat[33], q1); }
  __syncthreads();
  const int rep = blockIdx.x & 7;
  if (tid < 17)       atomicAdd(&stat0[rep*512 + v*J + tid], bstat[tid]);
  else if (tid < 34)  atomicAdd(&stat0[4096 + rep*512 + v*J + (tid-17)], bstat[tid]);
}

// -------- chain: BN_j (8-replica stats) -> bitmask adjacency -> ReLU [-> resid/F]
//          [-> conv_{j+1} (transposed W, 2-row pairing) -> replica stats]
// grid 512 x 16 rows, block 256 (4 waves; each wave 2 pairs of 2 rows)
template<int RESID,int WRITEF,int CONV>
__global__ __launch_bounds__(256) void chain_kernel(
  const float* __restrict__ Cin, float* __restrict__ Cout,
  float* __restrict__ F,
  const float* __restrict__ statJ,
  const float* __restrict__ g, const float* __restrict__ be,
  const float* __restrict__ Wc, const float* __restrict__ bc,
  float* __restrict__ statN)
{
  __shared__ float wsmT[J*J*JP];      // [v][o][d], d-contiguous
  __shared__ float bb[VO];
  __shared__ float aC[VO], cC[VO];
  __shared__ float hbX[4][2][J*JP];   // per-wave, 2 rows, [vertex][chan] padded
  __shared__ float ssum[VO], ssq[VO];
  const int tid = threadIdx.x, wv = tid>>6, lane = tid&63;

  if (CONV) {
    for (int i=tid;i<J*J*J;i+=256) {
      int v = i/VO, rem = i - v*VO, d = rem/J, o = rem - d*J;
      wsmT[(v*J+o)*JP + d] = Wc[i];
    }
    for (int i=tid;i<VO;i+=256) bb[i]=bc[i];
  }
  for (int i=tid;i<VO;i+=256) {
    float s=0.f,q=0.f;
    #pragma unroll
    for (int r=0;r<8;++r){ s += statJ[r*512+i]; q += statJ[4096 + r*512+i]; }
    float mu  = s*(1.f/NB);
    float var = q*(1.f/NB) - mu*mu;
    float rs  = rsqrtf(var + EPSB);
    float A = rs*g[i];
    aC[i]=A; cC[i]=be[i]-mu*A;
    ssum[i]=0.f; ssq[i]=0.f;
  }
  __syncthreads();

  float sl[5]={0,0,0,0,0}, ql[5]={0,0,0,0,0};

  #pragma unroll
  for (int it=0; it<2; ++it) {
    const int r0 = blockIdx.x*16 + wv*4 + it*2;   // rows r0, r0+1
    const float* c0 = Cin + (size_t)r0*VO;
    const float* c1 = c0 + VO;

    // 1: BN affine -> hbX  (layout [vertex*JP + chan])
    #pragma unroll
    for (int s=0;s<5;++s) {
      int vo = lane + 64*s;
      if (vo<VO) {
        int vtx = vo/J, o = vo - vtx*J;
        hbX[wv][0][vtx*JP+o] = c0[vo]*aC[vo] + cC[vo];
        hbX[wv][1][vtx*JP+o] = c1[vo]*aC[vo] + cC[vo];
      }
    }
    asm volatile("s_waitcnt lgkmcnt(0)" ::: "memory");

    // 2: bitmask adjacency + ReLU + resid -> regs
    float n0[5], n1[5];
    #pragma unroll
    for (int s=0;s<5;++s) {
      int vo = lane + 64*s;
      n0[s]=0.f; n1[s]=0.f;
      if (vo<VO) {
        int vtx = vo/J, o = vo - vtx*J;
        unsigned m = ADJM[vtx];
        float a0=0.f, a1=0.f;
        while (m) {
          int u = __ffs(m) - 1; m &= m-1;
          a0 += hbX[wv][0][u*JP+o];
          a1 += hbX[wv][1][u*JP+o];
        }
        a0 = a0>0.f?a0:0.f; a1 = a1>0.f?a1:0.f;
        size_t gi = (size_t)r0*VO + vo;
        if (RESID)  { a0 += F[gi]; a1 += F[gi+VO]; }
        if (WRITEF) { F[gi]=a0;    F[gi+VO]=a1; }
        n0[s]=a0; n1[s]=a1;
        if (!CONV) { Cout[gi]=a0; Cout[gi+VO]=a1; }
      }
    }

    if (CONV) {
      // 3: regs -> hbX (same-wave program order makes read-before-write safe)
      #pragma unroll
      for (int s=0;s<5;++s) {
        int vo = lane + 64*s;
        if (vo<VO) {
          int vtx = vo/J, o = vo - vtx*J;
          hbX[wv][0][vtx*JP+o] = n0[s];
          hbX[wv][1][vtx*JP+o] = n1[s];
        }
      }
      asm volatile("s_waitcnt lgkmcnt(0)" ::: "memory");
      // 4: conv with d-contiguous W and h, both rows share each W read
      #pragma unroll
      for (int s=0;s<5;++s) {
        int vo = lane + 64*s;
        if (vo<VO) {
          int vtx = vo/J, o = vo - vtx*J;
          const float* wp = &wsmT[(vtx*J+o)*JP];
          const float* h0 = &hbX[wv][0][vtx*JP];
          const float* h1 = &hbX[wv][1][vtx*JP];
          float a0 = bb[vo], a1 = a0;
          #pragma unroll
          for (int d=0;d<J;++d) {
            float w = wp[d];
            a0 += h0[d]*w; a1 += h1[d]*w;
          }
          size_t gi = (size_t)r0*VO + vo;
          Cout[gi]=a0; Cout[gi+VO]=a1;
          sl[s] += a0+a1; ql[s] += a0*a0 + a1*a1;
        }
      }
      asm volatile("s_waitcnt lgkmcnt(0)" ::: "memory");
    } else {
      asm volatile("s_waitcnt lgkmcnt(0)" ::: "memory");
    }
  }

  if (CONV) {
    #pragma unroll
    for (int s=0;s<5;++s) {
      int vo = lane + 64*s;
      if (vo<VO) { atomicAdd(&ssum[vo], sl[s]); atomicAdd(&ssq[vo], ql[s]); }
    }
    __syncthreads();
    const int rep = blockIdx.x & 7;
    for (int i=tid;i<VO;i+=256) {
      atomicAdd(&statN[rep*512+i],        ssum[i]);
      atomicAdd(&statN[4096 + rep*512+i], ssq[i]);
    }
  }
}

extern "C" void kernel_launch(void* const* d_in, const int* in_sizes, int n_in,
                              void* d_out, int out_size, void* d_ws, size_t ws_size,
                              hipStream_t stream)
{
  (void)in_sizes; (void)n_in; (void)out_size; (void)ws_size;
  const float* img = (const float*)d_in[0];
  const float* W0  = (const float*)d_in[1];
  const float* b0  = (const float*)d_in[2];
  const float* g0  = (const float*)d_in[3];
  const float* be0 = (const float*)d_in[4];
  const float* Wr  = (const float*)d_in[5];
  const float* br  = (const float*)d_in[6];
  const float* gr  = (const float*)d_in[7];
  const float* ber = (const float*)d_in[8];

  float* ws = (float*)d_ws;
  // stats: 9 stages x 8192 floats (8 replicas x 512 sum, then 8 x 512 sumsq)
  float* ST = ws;                              // 73728 floats
  unsigned short* Wbt = (unsigned short*)(ws + 73728);   // 1114112 ushorts = 557056 floats
  float* Ca = ws + 73728 + 557056;
  float* Cb = Ca + (size_t)NB*VO;
  float* F  = Cb + (size_t)NB*VO;
  float* out = (float*)d_out;

  zero_stats<<<72,256,0,stream>>>(ST, 9*8192);
  wconv_kernel<<<136,256,0,stream>>>(W0, Wbt);

  conv0_kernel<<<dim3(64,17),256,0,stream>>>(img, Wbt, b0, Ca, ST);

  const int W1 = J*J*J;
  #define STG(j) (ST + (j)*8192)
  // j=0: BN0(g0,be0) -> feat0 (store F), conv Wr[0] -> stats1
  chain_kernel<0,1,1><<<512,256,0,stream>>>(Ca, Cb, F, STG(0), g0,      be0,
                                            Wr+0*W1, br+0*VO, STG(1));
  chain_kernel<0,0,1><<<512,256,0,stream>>>(Cb, Ca, F, STG(1), gr+0*VO, ber+0*VO,
                                            Wr+1*W1, br+1*VO, STG(2));
  chain_kernel<1,1,1><<<512,256,0,stream>>>(Ca, Cb, F, STG(2), gr+1*VO, ber+1*VO,
                                            Wr+2*W1, br+2*VO, STG(3));
  chain_kernel<0,0,1><<<512,256,0,stream>>>(Cb, Ca, F, STG(3), gr+2*VO, ber+2*VO,
                                            Wr+3*W1, br+3*VO, STG(4));
  chain_kernel<1,1,1><<<512,256,0,stream>>>(Ca, Cb, F, STG(4), gr+3*VO, ber+3*VO,
                                            Wr+4*W1, br+4*VO, STG(5));
  chain_kernel<0,0,1><<<512,256,0,stream>>>(Cb, Ca, F, STG(5), gr+4*VO, ber+4*VO,
                                            Wr+5*W1, br+5*VO, STG(6));
  chain_kernel<1,1,1><<<512,256,0,stream>>>(Ca, Cb, F, STG(6), gr+5*VO, ber+5*VO,
                                            Wr+6*W1, br+6*VO, STG(7));
  chain_kernel<0,0,1><<<512,256,0,stream>>>(Cb, Ca, F, STG(7), gr+6*VO, ber+6*VO,
                                            Wr+7*W1, br+7*VO, STG(8));
  // j=8: BN8 -> adj -> relu -> + feat3 -> d_out
  chain_kernel<1,0,0><<<512,256,0,stream>>>(Ca, out, F, STG(8), gr+7*VO, ber+7*VO,
                                            nullptr, nullptr, nullptr);
  #undef STG
}